// Round 7
// baseline (3277.345 us; speedup 1.0000x reference)
//
#include <hip/hip_runtime.h>
#include <math.h>

#define BSZ 512
#define NV 30
#define NT 24
#define SS 768                  // state row stride (x: 0..249, m: 250..749, pad: 750..767)
#define PL (80 * 24 * 512)      // packed ushorts per (layer, half): 80 nb-blocks x 24 kc x 512
#define NBLK 256
#define NSTEP 144

typedef __attribute__((ext_vector_type(8))) short bf16x8;
typedef __attribute__((ext_vector_type(4))) float f32x4;

__device__ __forceinline__ unsigned short f2bf(float f) {
    unsigned u = __float_as_uint(f);
    u += 0x7fffu + ((u >> 16) & 1u);        // round-to-nearest-even
    return (unsigned short)(u >> 16);
}
__device__ __forceinline__ float bf2f(unsigned short h) {
    return __uint_as_float(((unsigned)h) << 16);
}
__device__ __forceinline__ f32x4 mm(bf16x8 a, bf16x8 b, f32x4 c) {
    return __builtin_amdgcn_mfma_f32_16x16x32_bf16(a, b, c, 0, 0, 0);
}
#define LD8(p) (*(const bf16x8*)(const void*)(p))

struct RecArgs {
    const unsigned short* Pw;
    unsigned short* A0hi; unsigned short* A0lo;
    unsigned short* A1hi; unsigned short* A1lo;
    float* Sfin;
    unsigned int* cnt; unsigned int* rel;
    const float* b1_sw; const float* b1_mem; const float* b1_sv;
    const float* b_sw;  const float* b_mem;  const float* b_sv;
    const float* w1_sw; const float* w1_mem; const float* w1_sv;
    const int* letters;
};

// ---------------- zero ----------------
__global__ void zero_kernel(float* p, int n) {
    int i = blockIdx.x * blockDim.x + threadIdx.x;
    int st = gridDim.x * blockDim.x;
    for (; i < n; i += st) p[i] = 0.f;
}

// ---------------- one-time weight pack: fp32 [750][N] -> hi/lo bf16 MFMA-B layout ----------------
// Phi[((nb*24 + kc)*64 + lane)*8 + j] = bf16_hi(W[kc*32 + (lane>>4)*8 + j][nb*16 + (lane&15)])
// nb 0..31 = sw (N=500 pad 512), 32..63 = mem, 64..79 = sv (N=250 pad 256). k>=750 zero-padded.
__launch_bounds__(64)
__global__ void pack_weights(const float* __restrict__ Wsw, const float* __restrict__ Wmem,
                             const float* __restrict__ Wsv,
                             unsigned short* __restrict__ Phi, unsigned short* __restrict__ Plo)
{
    const int kc = blockIdx.x;   // 0..23
    const int nb = blockIdx.y;   // 0..79
    const int l  = threadIdx.x;  // 0..63
    const int g = l >> 4, c = l & 15;
    const float* W; int N, nbl;
    if (nb < 32)      { W = Wsw;  N = 500; nbl = nb; }
    else if (nb < 64) { W = Wmem; N = 500; nbl = nb - 32; }
    else              { W = Wsv;  N = 250; nbl = nb - 64; }
    const int n = nbl * 16 + c;
    unsigned short h8[8], l8[8];
    #pragma unroll
    for (int j = 0; j < 8; ++j) {
        const int k = kc * 32 + g * 8 + j;
        const float w = (k < 750 && n < N) ? W[(size_t)k * N + n] : 0.f;
        const unsigned short h = f2bf(w);
        h8[j] = h;
        l8[j] = f2bf(w - bf2f(h));
    }
    const size_t off = ((size_t)nb * 24 + kc) * 512 + (size_t)l * 8;
    #pragma unroll
    for (int j = 0; j < 8; ++j) { Phi[off + j] = h8[j]; Plo[off + j] = l8[j]; }
}

// ---------------- persistent recurrence: all 24*6 layers in one kernel ----------------
// 256 blocks x 384 threads (6 waves): rg = bid>>3 owns 16 rows (48KB swizzled LDS);
// cx = bid&7 -> XCD under %8 round-robin; column-group cx owns sw units 4cx..+3 (+mem pair)
// and sv units 2cx..+1 for ALL layers => per-XCD weight slice 2.95MB. All 256 CUs active
// (round-6 used 128), doubling fetch MLP on the B-stream that round-6 counters showed is
// the bottleneck (8.1MB/step beyond-L2 at ~550GB/s = the 19.9us step time).
// PLUS: 4B touch-prefetch of the NEXT layer's B lines issued between compute and epilogue,
// sunk via asm after the epilogue -> fills overlap epilogue VALU + barrier skew; next
// step's B loads become L2 hits. Math order per output element is bit-identical to r5/r6
// (absmax canary 2.441e-4). Waves 0..3 = sw+mem pair (m carried in regs); 4..5 = sv.
// Cross-block state via relaxed agent-scope atomics; barrier = RMW arrive + RO release.
__launch_bounds__(384, 2)
__global__ void recurrence(RecArgs A)
{
    __shared__ __align__(16) unsigned char lds[49152];   // [plane 0=hi,1=lo][row 0..15][1536B, XOR-swizzled]
    const int tid = threadIdx.x;
    const int bid = blockIdx.x;
    const int w  = tid >> 6;        // wave 0..5
    const int l6 = tid & 63;
    const int g = l6 >> 4, c = l6 & 15;
    const int asw = (c & 7) << 4;   // FRAG XOR bits (row&7 == c&7)

    const int cx = bid & 7;         // column-group == XCD (under %8 round-robin)
    const int rg = bid >> 3;        // 0..31
    const int m0 = rg * 16;

    const bool ispair = (w < 4);
    const int u = ispair ? (4 * cx + w) : (2 * cx + (w - 4));
    const int col = u * 16 + c;     // pair: m-col (valid<500); sv: x-col (valid<250)

    const size_t lnoff = (size_t)l6 * 8;
    const size_t bofs0 = ((size_t)((ispair ? u : 64 + u) * 24)) * 512 + lnoff;
    const size_t bofs1 = ((size_t)((32 + u) * 24)) * 512 + lnoff;    // pair only

    float mreg[4];
    #pragma unroll
    for (int j = 0; j < 4; ++j) mreg[j] = 0.f;

#define FRAG(p, kc) (*(const bf16x8*)(lds + (p) * 24576 + c * 1536 + ((((kc) * 64) + g * 16) ^ asw)))

    #pragma unroll 1
    for (int step = 0; step < NSTEP; ++step) {
        const int t = step / 6;
        const int l = step - 6 * t;
        const unsigned short* Ahi = (step & 1) ? A.A1hi : A.A0hi;
        const unsigned short* Alo = (step & 1) ? A.A1lo : A.A0lo;
        unsigned short* Ohi = (step & 1) ? A.A0hi : A.A1hi;
        unsigned short* Olo = (step & 1) ? A.A0lo : A.A1lo;
        const unsigned short* Phi = A.Pw + (size_t)l * 2 * PL;
        const unsigned short* Plo = Phi + PL;
        const bool more = (step != NSTEP - 1);
        const int sn = step + 1;
        const int ln = sn - 6 * (sn / 6);
        const unsigned short* Pn = A.Pw + (size_t)ln * 2 * PL;   // next layer (prefetch)

        // ---- stage A rows [m0, m0+16), hi+lo, into swizzled LDS (coalesced 8B agent loads) ----
        // 16 rows x 192 chunks x 8B per plane = 3072 chunks; both planes per iter => 8 iters.
        {
            const unsigned long long* sh = (const unsigned long long*)(Ahi + (size_t)m0 * SS);
            const unsigned long long* sl = (const unsigned long long*)(Alo + (size_t)m0 * SS);
            #pragma unroll
            for (int j = 0; j < 8; ++j) {
                const int f = tid + j * 384;          // 8B chunk id, 0..3071 (= row*192 + ko/8)
                const int row = f / 192;
                const int ko = (f - row * 192) * 8;   // byte offset within row
                const int d = row * 1536 + (ko ^ ((row & 7) << 4));
                const unsigned long long vh = __hip_atomic_load(sh + f, __ATOMIC_RELAXED, __HIP_MEMORY_SCOPE_AGENT);
                const unsigned long long vl = __hip_atomic_load(sl + f, __ATOMIC_RELAXED, __HIP_MEMORY_SCOPE_AGENT);
                *(unsigned long long*)(lds + d) = vh;
                *(unsigned long long*)(lds + 24576 + d) = vl;
            }
        }
        __syncthreads();

        if (ispair) {
            f32x4 z0 = (f32x4)0.f, z1 = (f32x4)0.f;
            #pragma unroll 4
            for (int kc = 0; kc < 24; ++kc) {
                const bf16x8 ah = FRAG(0, kc);
                const bf16x8 al = FRAG(1, kc);
                const size_t k5 = (size_t)kc * 512;
                const bf16x8 bh0 = LD8(Phi + bofs0 + k5);
                const bf16x8 bl0 = LD8(Plo + bofs0 + k5);
                const bf16x8 bh1 = LD8(Phi + bofs1 + k5);
                const bf16x8 bl1 = LD8(Plo + bofs1 + k5);
                z0 = mm(ah, bh0, z0); z0 = mm(al, bh0, z0); z0 = mm(ah, bl0, z0);
                z1 = mm(ah, bh1, z1); z1 = mm(al, bh1, z1); z1 = mm(ah, bl1, z1);
            }
            // touch-prefetch next layer's B lines (4B per 16B fragment; fills whole 128B lines)
            unsigned pf = 0u;
            if (more) {
                #pragma unroll
                for (int kc = 0; kc < 24; ++kc) {
                    const size_t k5 = (size_t)kc * 512;
                    pf ^= *(const unsigned*)(const void*)(Pn + bofs0 + k5);
                    pf ^= *(const unsigned*)(const void*)(Pn + PL + bofs0 + k5);
                    pf ^= *(const unsigned*)(const void*)(Pn + bofs1 + k5);
                    pf ^= *(const unsigned*)(const void*)(Pn + PL + bofs1 + k5);
                }
            }
            if (col < 500) {
                const float* bswp  = l ? A.b_sw  + (size_t)(l - 1) * 500 : A.b1_sw;
                const float* bmemp = l ? A.b_mem + (size_t)(l - 1) * 500 : A.b1_mem;
                const float bs = bswp[col];
                const float bm = bmemp[col];
                #pragma unroll
                for (int r = 0; r < 4; ++r) {
                    const int row = m0 + g * 4 + r;
                    float zs = z0[r] + bs;
                    float zm = z1[r] + bm;
                    if (l == 0) {
                        const int lt = A.letters[row * NT + t];
                        zs += A.w1_sw[(size_t)(750 + lt) * 500 + col];
                        zm += A.w1_mem[(size_t)(750 + lt) * 500 + col];
                    }
                    const float s = 1.f / (1.f + expf(-zs));
                    const float mn = mreg[r] * s + tanhf(zm) * (1.f - s);
                    mreg[r] = mn;
                    const size_t o = (size_t)row * SS + 250 + col;
                    const unsigned short h = f2bf(mn);
                    const unsigned short lo2 = f2bf(mn - bf2f(h));
                    __hip_atomic_store(Ohi + o, h, __ATOMIC_RELAXED, __HIP_MEMORY_SCOPE_AGENT);
                    __hip_atomic_store(Olo + o, lo2, __ATOMIC_RELAXED, __HIP_MEMORY_SCOPE_AGENT);
                    if (step == NSTEP - 1) A.Sfin[o] = mn;
                }
            }
            asm volatile("" :: "v"(pf));     // keep prefetch loads alive; fills overlap epilogue
        } else {
            f32x4 z0 = (f32x4)0.f;
            #pragma unroll 4
            for (int kc = 0; kc < 24; ++kc) {
                const bf16x8 ah = FRAG(0, kc);
                const bf16x8 al = FRAG(1, kc);
                const size_t k5 = (size_t)kc * 512;
                const bf16x8 bh = LD8(Phi + bofs0 + k5);
                const bf16x8 bl = LD8(Plo + bofs0 + k5);
                z0 = mm(ah, bh, z0); z0 = mm(al, bh, z0); z0 = mm(ah, bl, z0);
            }
            unsigned pf = 0u;
            if (more) {
                #pragma unroll
                for (int kc = 0; kc < 24; ++kc) {
                    const size_t k5 = (size_t)kc * 512;
                    pf ^= *(const unsigned*)(const void*)(Pn + bofs0 + k5);
                    pf ^= *(const unsigned*)(const void*)(Pn + PL + bofs0 + k5);
                }
            }
            if (col < 250) {
                const float* bsvp = l ? A.b_sv + (size_t)(l - 1) * 250 : A.b1_sv;
                const float bv = bsvp[col];
                #pragma unroll
                for (int r = 0; r < 4; ++r) {
                    const int row = m0 + g * 4 + r;
                    float z = z0[r] + bv;
                    if (l == 0) {
                        const int lt = A.letters[row * NT + t];
                        z += A.w1_sv[(size_t)(750 + lt) * 250 + col];
                    }
                    const float x = tanhf(z);
                    const size_t o = (size_t)row * SS + col;
                    const unsigned short h = f2bf(x);
                    const unsigned short lo2 = f2bf(x - bf2f(h));
                    __hip_atomic_store(Ohi + o, h, __ATOMIC_RELAXED, __HIP_MEMORY_SCOPE_AGENT);
                    __hip_atomic_store(Olo + o, lo2, __ATOMIC_RELAXED, __HIP_MEMORY_SCOPE_AGENT);
                    if (step == NSTEP - 1) A.Sfin[o] = x;
                }
            }
            asm volatile("" :: "v"(pf));
        }

        // ---- grid barrier: RMW arrivals on cnt, spin on read-only release word ----
        __syncthreads();                         // drains vmcnt: this block's sc1 stores visible @ MALL
        if (more) {
            if (tid == 0) {
                const unsigned v = __hip_atomic_fetch_add(A.cnt, 1u, __ATOMIC_RELAXED, __HIP_MEMORY_SCOPE_AGENT);
                if (v == (unsigned)NBLK * (unsigned)(step + 1) - 1u) {
                    __hip_atomic_store(A.rel, (unsigned)(step + 1), __ATOMIC_RELAXED, __HIP_MEMORY_SCOPE_AGENT);
                } else {
                    while (__hip_atomic_load(A.rel, __ATOMIC_RELAXED, __HIP_MEMORY_SCOPE_AGENT) < (unsigned)(step + 1))
                        __builtin_amdgcn_s_sleep(2);
                }
            }
            __syncthreads();
        }
    }
#undef FRAG
}

// ---------------- head GEMM: Y = tanh(X @ W + b) (fp32) ----------------
__launch_bounds__(128)
__global__ void head_gemm(const float* __restrict__ X, int ldx, int K,
                          const float* __restrict__ W, const float* __restrict__ bias,
                          float* __restrict__ Y, int N)
{
    const int tid = threadIdx.x;
    const int m0 = blockIdx.y * 32;
    const int n0 = blockIdx.x * 64;

    __shared__ float As[2][32][36];
    __shared__ float Bs[2][32][68];

    const int tx = tid & 15, ty = tid >> 4;
    const int kl = tid & 31, rl = tid >> 5;
    const int cl = tid & 63, kg = tid >> 6;
    const bool cok = (n0 + cl) < N;

    float acc[4][4] = {{0.f}};
    float ar[8], br[16];

    {
        const float* a = X + (size_t)(m0 + rl) * ldx + kl;
        #pragma unroll
        for (int i = 0; i < 8; i++) ar[i] = a[(size_t)(4 * i) * ldx];
        #pragma unroll
        for (int i = 0; i < 16; i++)
            br[i] = cok ? W[(size_t)(kg + 2 * i) * N + n0 + cl] : 0.f;
        #pragma unroll
        for (int i = 0; i < 8; i++) As[0][kl][rl + 4 * i] = ar[i];
        #pragma unroll
        for (int i = 0; i < 16; i++) Bs[0][kg + 2 * i][cl] = br[i];
    }
    __syncthreads();

    int buf = 0;
    const int NK = (K + 31) / 32;
    #pragma unroll 1
    for (int kt = 0; kt < NK; kt++) {
        const bool more = (kt + 1 < NK);
        if (more) {
            const int k0 = (kt + 1) * 32;
            const bool ka = (k0 + kl) < K;
            const float* a = X + (size_t)(m0 + rl) * ldx + k0 + kl;
            #pragma unroll
            for (int i = 0; i < 8; i++) ar[i] = ka ? a[(size_t)(4 * i) * ldx] : 0.f;
            #pragma unroll
            for (int i = 0; i < 16; i++) {
                const int kk = k0 + kg + 2 * i;
                br[i] = (cok && kk < K) ? W[(size_t)kk * N + n0 + cl] : 0.f;
            }
        }
        #pragma unroll
        for (int kk = 0; kk < 32; kk++) {
            float4 av = *(const float4*)&As[buf][kk][ty * 4];
            float4 bv = *(const float4*)&Bs[buf][kk][tx * 4];
            const float aa[4] = {av.x, av.y, av.z, av.w};
            const float bb[4] = {bv.x, bv.y, bv.z, bv.w};
            #pragma unroll
            for (int i = 0; i < 4; i++)
                #pragma unroll
                for (int j = 0; j < 4; j++)
                    acc[i][j] = fmaf(aa[i], bb[j], acc[i][j]);
        }
        if (more) {
            #pragma unroll
            for (int i = 0; i < 8; i++) As[buf ^ 1][kl][rl + 4 * i] = ar[i];
            #pragma unroll
            for (int i = 0; i < 16; i++) Bs[buf ^ 1][kg + 2 * i][cl] = br[i];
            __syncthreads();
            buf ^= 1;
        }
    }

    #pragma unroll
    for (int i = 0; i < 4; i++) {
        const int b = m0 + ty * 4 + i;
        #pragma unroll
        for (int j = 0; j < 4; j++) {
            const int n = n0 + tx * 4 + j;
            if (n < N) Y[(size_t)b * N + n] = tanhf(acc[i][j] + bias[n]);
        }
    }
}

// ---------------- final: logits (K=100, N=30) + softmax ----------------
__global__ void head_final(const float* __restrict__ Y4, const float* __restrict__ W,
                           const float* __restrict__ bias, float* __restrict__ out)
{
    const int row = blockIdx.x;
    __shared__ float y[100];
    __shared__ float z[NV];
    for (int k = threadIdx.x; k < 100; k += 64) y[k] = Y4[row * 100 + k];
    __syncthreads();
    const int n = threadIdx.x;
    if (n < NV) {
        float acc = bias[n];
        for (int k = 0; k < 100; k++) acc = fmaf(y[k], W[k * NV + n], acc);
        z[n] = acc;
    }
    __syncthreads();
    if (n < NV) {
        float mx = -1e30f;
        for (int i = 0; i < NV; i++) mx = fmaxf(mx, z[i]);
        float sum = 0.f;
        for (int i = 0; i < NV; i++) sum += expf(z[i] - mx);
        out[row * NV + n] = expf(z[n] - mx) / sum;
    }
}

extern "C" void kernel_launch(void* const* d_in, const int* in_sizes, int n_in,
                              void* d_out, int out_size, void* d_ws, size_t ws_size,
                              hipStream_t stream)
{
    const int*   letters = (const int*)  d_in[0];
    const float* w1_sv   = (const float*)d_in[1];
    const float* b1_sv   = (const float*)d_in[2];
    const float* w1_mem  = (const float*)d_in[3];
    const float* b1_mem  = (const float*)d_in[4];
    const float* w1_sw   = (const float*)d_in[5];
    const float* b1_sw   = (const float*)d_in[6];
    const float* w_sv    = (const float*)d_in[7];
    const float* b_sv    = (const float*)d_in[8];
    const float* w_mem   = (const float*)d_in[9];
    const float* b_mem   = (const float*)d_in[10];
    const float* w_sw    = (const float*)d_in[11];
    const float* b_sw    = (const float*)d_in[12];
    const float* wp1 = (const float*)d_in[13]; const float* bp1 = (const float*)d_in[14];
    const float* wp2 = (const float*)d_in[15]; const float* bp2 = (const float*)d_in[16];
    const float* wp3 = (const float*)d_in[17]; const float* bp3 = (const float*)d_in[18];
    const float* wp4 = (const float*)d_in[19]; const float* bp4 = (const float*)d_in[20];
    const float* wp5 = (const float*)d_in[21]; const float* bp5 = (const float*)d_in[22];

    // workspace layout
    float* Sfin = (float*)d_ws;                                   // BSZ*SS f32 (written at final step)
    float* cntf = Sfin + (size_t)BSZ * SS;                        // 64 f32: cnt line + rel line
    unsigned int* cnt = (unsigned int*)cntf;
    unsigned int* rel = cnt + 32;                                 // separate 128B line
    unsigned short* A0hi = (unsigned short*)(cntf + 64);
    unsigned short* A0lo = A0hi + (size_t)BSZ * SS;
    unsigned short* A1hi = A0lo + (size_t)BSZ * SS;
    unsigned short* A1lo = A1hi + (size_t)BSZ * SS;
    unsigned short* Pw   = A1lo + (size_t)BSZ * SS;               // 12 * PL ushorts
    float* Y1 = (float*)(Pw + (size_t)12 * PL);
    float* Y2 = Y1 + (size_t)BSZ * 450;
    float* Y3 = Y2 + (size_t)BSZ * 300;
    float* Y4 = Y3 + (size_t)BSZ * 200;

    // zero barrier words + all 4 bf16 state planes (incl. K-pad cols, which stay 0 forever)
    zero_kernel<<<512, 256, 0, stream>>>(cntf, 64 + 2 * BSZ * SS);

    // one-time weight packing
    pack_weights<<<dim3(24, 80), 64, 0, stream>>>(w1_sw, w1_mem, w1_sv, Pw, Pw + PL);
    for (int l = 1; l < 6; ++l)
        pack_weights<<<dim3(24, 80), 64, 0, stream>>>(
            w_sw  + (size_t)(l - 1) * 750 * 500,
            w_mem + (size_t)(l - 1) * 750 * 500,
            w_sv  + (size_t)(l - 1) * 750 * 250,
            Pw + (size_t)l * 2 * PL, Pw + (size_t)l * 2 * PL + PL);

    RecArgs ra;
    ra.Pw = Pw;
    ra.A0hi = A0hi; ra.A0lo = A0lo; ra.A1hi = A1hi; ra.A1lo = A1lo;
    ra.Sfin = Sfin; ra.cnt = cnt; ra.rel = rel;
    ra.b1_sw = b1_sw; ra.b1_mem = b1_mem; ra.b1_sv = b1_sv;
    ra.b_sw = b_sw;   ra.b_mem = b_mem;   ra.b_sv = b_sv;
    ra.w1_sw = w1_sw; ra.w1_mem = w1_mem; ra.w1_sv = w1_sv;
    ra.letters = letters;
    recurrence<<<NBLK, 384, 0, stream>>>(ra);

    head_gemm<<<dim3(8, 16), 128, 0, stream>>>(Sfin, SS, 750, wp1, bp1, Y1, 450);
    head_gemm<<<dim3(5, 16), 128, 0, stream>>>(Y1, 450, 450, wp2, bp2, Y2, 300);
    head_gemm<<<dim3(4, 16), 128, 0, stream>>>(Y2, 300, 300, wp3, bp3, Y3, 200);
    head_gemm<<<dim3(2, 16), 128, 0, stream>>>(Y3, 200, 200, wp4, bp4, Y4, 100);
    head_final<<<BSZ, 64, 0, stream>>>(Y4, wp5, bp5, (float*)d_out);
}

// Round 8
// 2852.354 us; speedup vs baseline: 1.1490x; 1.1490x over previous
//
#include <hip/hip_runtime.h>
#include <math.h>

#define BSZ 512
#define NV 30
#define NT 24
#define SS 768                  // state row stride (x: 0..249, m: 250..749, pad: 750..767)
#define PL (80 * 24 * 512)      // packed ushorts per (layer, half): 80 nb-blocks x 24 kc x 512
#define NGRID 512               // launched blocks (2/CU capacity => all co-resident)
#define NWORK 256               // working blocks (32 per XCD via hardware ticket)
#define NSTEP 144

typedef __attribute__((ext_vector_type(8))) short bf16x8;
typedef __attribute__((ext_vector_type(4))) float f32x4;

__device__ __forceinline__ unsigned short f2bf(float f) {
    unsigned u = __float_as_uint(f);
    u += 0x7fffu + ((u >> 16) & 1u);        // round-to-nearest-even
    return (unsigned short)(u >> 16);
}
__device__ __forceinline__ float bf2f(unsigned short h) {
    return __uint_as_float(((unsigned)h) << 16);
}
__device__ __forceinline__ f32x4 mm(bf16x8 a, bf16x8 b, f32x4 c) {
    return __builtin_amdgcn_mfma_f32_16x16x32_bf16(a, b, c, 0, 0, 0);
}
#define LD8(p) (*(const bf16x8*)(const void*)(p))

struct RecArgs {
    const unsigned short* Pw;
    unsigned* A0; unsigned* A1;      // interleaved state planes: elem = hi | (lo<<16)
    float* Sfin;
    unsigned int* cnt; unsigned int* rel; unsigned int* ticket;   // ticket[8]
    const float* b1_sw; const float* b1_mem; const float* b1_sv;
    const float* b_sw;  const float* b_mem;  const float* b_sv;
    const float* w1_sw; const float* w1_mem; const float* w1_sv;
    const int* letters;
};

// ---------------- zero ----------------
__global__ void zero_kernel(float* p, int n) {
    int i = blockIdx.x * blockDim.x + threadIdx.x;
    int st = gridDim.x * blockDim.x;
    for (; i < n; i += st) p[i] = 0.f;
}

// ---------------- one-time weight pack: fp32 [750][N] -> hi/lo bf16 MFMA-B layout ----------------
// Phi[((nb*24 + kc)*64 + lane)*8 + j] = bf16_hi(W[kc*32 + (lane>>4)*8 + j][nb*16 + (lane&15)])
// nb 0..31 = sw (N=500 pad 512), 32..63 = mem, 64..79 = sv (N=250 pad 256). k>=750 zero-padded.
__launch_bounds__(64)
__global__ void pack_weights(const float* __restrict__ Wsw, const float* __restrict__ Wmem,
                             const float* __restrict__ Wsv,
                             unsigned short* __restrict__ Phi, unsigned short* __restrict__ Plo)
{
    const int kc = blockIdx.x;   // 0..23
    const int nb = blockIdx.y;   // 0..79
    const int l  = threadIdx.x;  // 0..63
    const int g = l >> 4, c = l & 15;
    const float* W; int N, nbl;
    if (nb < 32)      { W = Wsw;  N = 500; nbl = nb; }
    else if (nb < 64) { W = Wmem; N = 500; nbl = nb - 32; }
    else              { W = Wsv;  N = 250; nbl = nb - 64; }
    const int n = nbl * 16 + c;
    unsigned short h8[8], l8[8];
    #pragma unroll
    for (int j = 0; j < 8; ++j) {
        const int k = kc * 32 + g * 8 + j;
        const float w = (k < 750 && n < N) ? W[(size_t)k * N + n] : 0.f;
        const unsigned short h = f2bf(w);
        h8[j] = h;
        l8[j] = f2bf(w - bf2f(h));
    }
    const size_t off = ((size_t)nb * 24 + kc) * 512 + (size_t)l * 8;
    #pragma unroll
    for (int j = 0; j < 8; ++j) { Phi[off + j] = h8[j]; Plo[off + j] = l8[j]; }
}

// ---------------- persistent recurrence: all 24*6 layers in one kernel ----------------
// 512 blocks x 384 threads, 2 blocks/CU (48KB LDS, VGPR capped by launch_bounds(384,3)).
// Capacity = 8 XCD x 32 CU x 2 = 512 = grid => ALL blocks co-resident => pigeonhole:
// each XCD hosts exactly 64 blocks. cx = HARDWARE XCC_ID (s_getreg, m09-verified) --
// not a bid%8 guess (r6/r7 FETCH=2x weights/step proved that guess wrong). rg = per-XCD
// atomic ticket; first 32 tickets/XCD work (rows rg*16..+15), rest exit. Column-group cx
// owns sw units 4cx..+3 (+mem pair) + sv units 2cx..+1 for ALL layers => per-XCD weight
// slice 2.95MB < 4MB L2, resident by construction => B loads become L2 hits after epoch 1.
// State: ONE interleaved u32 plane (hi|lo<<16) exchanged via relaxed agent-scope (sc1)
// atomics @ MALL; math order identical to r3..r7 => absmax canary 2.441e-4 must hold.
// Grid barrier: RMW-arrive counter + read-only release word, 256 arrivals.
__launch_bounds__(384, 3)
__global__ void recurrence(RecArgs A)
{
    __shared__ __align__(16) unsigned char lds[49152];   // [plane 0=hi,1=lo][row 0..15][1536B, XOR-swizzled]
    __shared__ int s_rg;
    const int tid = threadIdx.x;

    int xcd;
    asm volatile("s_getreg_b32 %0, hwreg(HW_REG_XCC_ID)" : "=s"(xcd));
    if (tid == 0) s_rg = (int)atomicAdd(A.ticket + (xcd & 7), 1u);
    __syncthreads();
    const int rg = s_rg;
    if (rg >= 32) return;                  // surplus block
    const int cx = xcd & 7;
    const int m0 = rg * 16;

    const int w  = tid >> 6;        // wave 0..5
    const int l6 = tid & 63;
    const int g = l6 >> 4, c = l6 & 15;
    const int asw = (c & 7) << 4;   // FRAG XOR bits (row&7 == c&7)

    const bool ispair = (w < 4);
    const int u = ispair ? (4 * cx + w) : (2 * cx + (w - 4));
    const int col = u * 16 + c;     // pair: m-col (valid<500); sv: x-col (valid<250)

    const size_t lnoff = (size_t)l6 * 8;
    const size_t bofs0 = ((size_t)((ispair ? u : 64 + u) * 24)) * 512 + lnoff;
    const size_t bofs1 = ((size_t)((32 + u) * 24)) * 512 + lnoff;    // pair only

    float mreg[4];
    #pragma unroll
    for (int j = 0; j < 4; ++j) mreg[j] = 0.f;

#define FRAG(p, kc) (*(const bf16x8*)(lds + (p) * 24576 + c * 1536 + ((((kc) * 64) + g * 16) ^ asw)))

    #pragma unroll 1
    for (int step = 0; step < NSTEP; ++step) {
        const int t = step / 6;
        const int l = step - 6 * t;
        const unsigned* Ain = (step & 1) ? A.A1 : A.A0;
        unsigned* Aout      = (step & 1) ? A.A0 : A.A1;
        const unsigned short* Phi = A.Pw + (size_t)l * 2 * PL;
        const unsigned short* Plo = Phi + PL;
        const bool more = (step != NSTEP - 1);

        // ---- stage A rows [m0, m0+16): 16 rows x 384 u64-chunks (2 packed elems each)
        // = 6144 chunks / 384 threads = 16 iters of coalesced 8B agent loads; unpack
        // hi/lo into the two swizzled LDS planes (identical layout to prior rounds).
        {
            const unsigned long long* sp = (const unsigned long long*)(Ain + (size_t)m0 * SS);
            #pragma unroll
            for (int j = 0; j < 16; ++j) {
                const int f = tid + j * 384;          // u64 chunk id, 0..6143 (= row*384 + q)
                const int row = f / 384;
                const int q = f - row * 384;          // u64 chunk within row -> cols 2q, 2q+1
                const int ko = q * 4;                 // byte offset within bf16-plane row
                const int d = row * 1536 + (ko ^ ((row & 7) << 4));
                const unsigned long long p = __hip_atomic_load(sp + f, __ATOMIC_RELAXED, __HIP_MEMORY_SCOPE_AGENT);
                const unsigned lo32 = (unsigned)p, hi32 = (unsigned)(p >> 32);
                *(unsigned*)(lds + d)         = (lo32 & 0xffffu) | (hi32 << 16);          // hi parts
                *(unsigned*)(lds + 24576 + d) = (lo32 >> 16) | (hi32 & 0xffff0000u);      // lo parts
            }
        }
        __syncthreads();

        if (ispair) {
            f32x4 z0 = (f32x4)0.f, z1 = (f32x4)0.f;
            #pragma unroll 4
            for (int kc = 0; kc < 24; ++kc) {
                const bf16x8 ah = FRAG(0, kc);
                const bf16x8 al = FRAG(1, kc);
                const size_t k5 = (size_t)kc * 512;
                const bf16x8 bh0 = LD8(Phi + bofs0 + k5);
                const bf16x8 bl0 = LD8(Plo + bofs0 + k5);
                const bf16x8 bh1 = LD8(Phi + bofs1 + k5);
                const bf16x8 bl1 = LD8(Plo + bofs1 + k5);
                z0 = mm(ah, bh0, z0); z0 = mm(al, bh0, z0); z0 = mm(ah, bl0, z0);
                z1 = mm(ah, bh1, z1); z1 = mm(al, bh1, z1); z1 = mm(ah, bl1, z1);
            }
            if (col < 500) {
                const float* bswp  = l ? A.b_sw  + (size_t)(l - 1) * 500 : A.b1_sw;
                const float* bmemp = l ? A.b_mem + (size_t)(l - 1) * 500 : A.b1_mem;
                const float bs = bswp[col];
                const float bm = bmemp[col];
                #pragma unroll
                for (int r = 0; r < 4; ++r) {
                    const int row = m0 + g * 4 + r;
                    float zs = z0[r] + bs;
                    float zm = z1[r] + bm;
                    if (l == 0) {
                        const int lt = A.letters[row * NT + t];
                        zs += A.w1_sw[(size_t)(750 + lt) * 500 + col];
                        zm += A.w1_mem[(size_t)(750 + lt) * 500 + col];
                    }
                    const float s = 1.f / (1.f + expf(-zs));
                    const float mn = mreg[r] * s + tanhf(zm) * (1.f - s);
                    mreg[r] = mn;
                    const size_t o = (size_t)row * SS + 250 + col;
                    const unsigned short h = f2bf(mn);
                    const unsigned short lo2 = f2bf(mn - bf2f(h));
                    __hip_atomic_store(Aout + o, (unsigned)h | ((unsigned)lo2 << 16),
                                       __ATOMIC_RELAXED, __HIP_MEMORY_SCOPE_AGENT);
                    if (step == NSTEP - 1) A.Sfin[o] = mn;
                }
            }
        } else {
            f32x4 z0 = (f32x4)0.f;
            #pragma unroll 4
            for (int kc = 0; kc < 24; ++kc) {
                const bf16x8 ah = FRAG(0, kc);
                const bf16x8 al = FRAG(1, kc);
                const size_t k5 = (size_t)kc * 512;
                const bf16x8 bh = LD8(Phi + bofs0 + k5);
                const bf16x8 bl = LD8(Plo + bofs0 + k5);
                z0 = mm(ah, bh, z0); z0 = mm(al, bh, z0); z0 = mm(ah, bl, z0);
            }
            if (col < 250) {
                const float* bsvp = l ? A.b_sv + (size_t)(l - 1) * 250 : A.b1_sv;
                const float bv = bsvp[col];
                #pragma unroll
                for (int r = 0; r < 4; ++r) {
                    const int row = m0 + g * 4 + r;
                    float z = z0[r] + bv;
                    if (l == 0) {
                        const int lt = A.letters[row * NT + t];
                        z += A.w1_sv[(size_t)(750 + lt) * 250 + col];
                    }
                    const float x = tanhf(z);
                    const size_t o = (size_t)row * SS + col;
                    const unsigned short h = f2bf(x);
                    const unsigned short lo2 = f2bf(x - bf2f(h));
                    __hip_atomic_store(Aout + o, (unsigned)h | ((unsigned)lo2 << 16),
                                       __ATOMIC_RELAXED, __HIP_MEMORY_SCOPE_AGENT);
                    if (step == NSTEP - 1) A.Sfin[o] = x;
                }
            }
        }

        // ---- grid barrier: RMW arrivals on cnt, spin on read-only release word ----
        __syncthreads();                         // drains vmcnt: this block's sc1 stores visible @ MALL
        if (more) {
            if (tid == 0) {
                const unsigned v = __hip_atomic_fetch_add(A.cnt, 1u, __ATOMIC_RELAXED, __HIP_MEMORY_SCOPE_AGENT);
                if (v == (unsigned)NWORK * (unsigned)(step + 1) - 1u) {
                    __hip_atomic_store(A.rel, (unsigned)(step + 1), __ATOMIC_RELAXED, __HIP_MEMORY_SCOPE_AGENT);
                } else {
                    while (__hip_atomic_load(A.rel, __ATOMIC_RELAXED, __HIP_MEMORY_SCOPE_AGENT) < (unsigned)(step + 1))
                        __builtin_amdgcn_s_sleep(2);
                }
            }
            __syncthreads();
        }
    }
#undef FRAG
}

// ---------------- head GEMM: Y = tanh(X @ W + b) (fp32) ----------------
__launch_bounds__(128)
__global__ void head_gemm(const float* __restrict__ X, int ldx, int K,
                          const float* __restrict__ W, const float* __restrict__ bias,
                          float* __restrict__ Y, int N)
{
    const int tid = threadIdx.x;
    const int m0 = blockIdx.y * 32;
    const int n0 = blockIdx.x * 64;

    __shared__ float As[2][32][36];
    __shared__ float Bs[2][32][68];

    const int tx = tid & 15, ty = tid >> 4;
    const int kl = tid & 31, rl = tid >> 5;
    const int cl = tid & 63, kg = tid >> 6;
    const bool cok = (n0 + cl) < N;

    float acc[4][4] = {{0.f}};
    float ar[8], br[16];

    {
        const float* a = X + (size_t)(m0 + rl) * ldx + kl;
        #pragma unroll
        for (int i = 0; i < 8; i++) ar[i] = a[(size_t)(4 * i) * ldx];
        #pragma unroll
        for (int i = 0; i < 16; i++)
            br[i] = cok ? W[(size_t)(kg + 2 * i) * N + n0 + cl] : 0.f;
        #pragma unroll
        for (int i = 0; i < 8; i++) As[0][kl][rl + 4 * i] = ar[i];
        #pragma unroll
        for (int i = 0; i < 16; i++) Bs[0][kg + 2 * i][cl] = br[i];
    }
    __syncthreads();

    int buf = 0;
    const int NK = (K + 31) / 32;
    #pragma unroll 1
    for (int kt = 0; kt < NK; kt++) {
        const bool more = (kt + 1 < NK);
        if (more) {
            const int k0 = (kt + 1) * 32;
            const bool ka = (k0 + kl) < K;
            const float* a = X + (size_t)(m0 + rl) * ldx + k0 + kl;
            #pragma unroll
            for (int i = 0; i < 8; i++) ar[i] = ka ? a[(size_t)(4 * i) * ldx] : 0.f;
            #pragma unroll
            for (int i = 0; i < 16; i++) {
                const int kk = k0 + kg + 2 * i;
                br[i] = (cok && kk < K) ? W[(size_t)kk * N + n0 + cl] : 0.f;
            }
        }
        #pragma unroll
        for (int kk = 0; kk < 32; kk++) {
            float4 av = *(const float4*)&As[buf][kk][ty * 4];
            float4 bv = *(const float4*)&Bs[buf][kk][tx * 4];
            const float aa[4] = {av.x, av.y, av.z, av.w};
            const float bb[4] = {bv.x, bv.y, bv.z, bv.w};
            #pragma unroll
            for (int i = 0; i < 4; i++)
                #pragma unroll
                for (int j = 0; j < 4; j++)
                    acc[i][j] = fmaf(aa[i], bb[j], acc[i][j]);
        }
        if (more) {
            #pragma unroll
            for (int i = 0; i < 8; i++) As[buf ^ 1][kl][rl + 4 * i] = ar[i];
            #pragma unroll
            for (int i = 0; i < 16; i++) Bs[buf ^ 1][kg + 2 * i][cl] = br[i];
            __syncthreads();
            buf ^= 1;
        }
    }

    #pragma unroll
    for (int i = 0; i < 4; i++) {
        const int b = m0 + ty * 4 + i;
        #pragma unroll
        for (int j = 0; j < 4; j++) {
            const int n = n0 + tx * 4 + j;
            if (n < N) Y[(size_t)b * N + n] = tanhf(acc[i][j] + bias[n]);
        }
    }
}

// ---------------- final: logits (K=100, N=30) + softmax ----------------
__global__ void head_final(const float* __restrict__ Y4, const float* __restrict__ W,
                           const float* __restrict__ bias, float* __restrict__ out)
{
    const int row = blockIdx.x;
    __shared__ float y[100];
    __shared__ float z[NV];
    for (int k = threadIdx.x; k < 100; k += 64) y[k] = Y4[row * 100 + k];
    __syncthreads();
    const int n = threadIdx.x;
    if (n < NV) {
        float acc = bias[n];
        for (int k = 0; k < 100; k++) acc = fmaf(y[k], W[k * NV + n], acc);
        z[n] = acc;
    }
    __syncthreads();
    if (n < NV) {
        float mx = -1e30f;
        for (int i = 0; i < NV; i++) mx = fmaxf(mx, z[i]);
        float sum = 0.f;
        for (int i = 0; i < NV; i++) sum += expf(z[i] - mx);
        out[row * NV + n] = expf(z[n] - mx) / sum;
    }
}

extern "C" void kernel_launch(void* const* d_in, const int* in_sizes, int n_in,
                              void* d_out, int out_size, void* d_ws, size_t ws_size,
                              hipStream_t stream)
{
    const int*   letters = (const int*)  d_in[0];
    const float* w1_sv   = (const float*)d_in[1];
    const float* b1_sv   = (const float*)d_in[2];
    const float* w1_mem  = (const float*)d_in[3];
    const float* b1_mem  = (const float*)d_in[4];
    const float* w1_sw   = (const float*)d_in[5];
    const float* b1_sw   = (const float*)d_in[6];
    const float* w_sv    = (const float*)d_in[7];
    const float* b_sv    = (const float*)d_in[8];
    const float* w_mem   = (const float*)d_in[9];
    const float* b_mem   = (const float*)d_in[10];
    const float* w_sw    = (const float*)d_in[11];
    const float* b_sw    = (const float*)d_in[12];
    const float* wp1 = (const float*)d_in[13]; const float* bp1 = (const float*)d_in[14];
    const float* wp2 = (const float*)d_in[15]; const float* bp2 = (const float*)d_in[16];
    const float* wp3 = (const float*)d_in[17]; const float* bp3 = (const float*)d_in[18];
    const float* wp4 = (const float*)d_in[19]; const float* bp4 = (const float*)d_in[20];
    const float* wp5 = (const float*)d_in[21]; const float* bp5 = (const float*)d_in[22];

    // workspace layout
    float* Sfin = (float*)d_ws;                                   // BSZ*SS f32 (written at final step)
    float* cntf = Sfin + (size_t)BSZ * SS;                        // 128 u32: cnt, rel, ticket[8]
    unsigned int* cnt = (unsigned int*)cntf;
    unsigned int* rel = cnt + 32;                                 // separate 128B line
    unsigned int* ticket = cnt + 64;                              // 8 per-XCD tickets
    unsigned* A0 = (unsigned*)(cntf + 128);                       // interleaved state plane 0
    unsigned* A1 = A0 + (size_t)BSZ * SS;                         // interleaved state plane 1
    unsigned short* Pw = (unsigned short*)(A1 + (size_t)BSZ * SS);// 12 * PL ushorts
    float* Y1 = (float*)(Pw + (size_t)12 * PL);
    float* Y2 = Y1 + (size_t)BSZ * 450;
    float* Y3 = Y2 + (size_t)BSZ * 300;
    float* Y4 = Y3 + (size_t)BSZ * 200;

    // zero barrier words + tickets + both interleaved state planes (pad cols stay 0 forever)
    zero_kernel<<<512, 256, 0, stream>>>(cntf, 128 + 2 * BSZ * SS);

    // one-time weight packing
    pack_weights<<<dim3(24, 80), 64, 0, stream>>>(w1_sw, w1_mem, w1_sv, Pw, Pw + PL);
    for (int l = 1; l < 6; ++l)
        pack_weights<<<dim3(24, 80), 64, 0, stream>>>(
            w_sw  + (size_t)(l - 1) * 750 * 500,
            w_mem + (size_t)(l - 1) * 750 * 500,
            w_sv  + (size_t)(l - 1) * 750 * 250,
            Pw + (size_t)l * 2 * PL, Pw + (size_t)l * 2 * PL + PL);

    RecArgs ra;
    ra.Pw = Pw;
    ra.A0 = A0; ra.A1 = A1;
    ra.Sfin = Sfin; ra.cnt = cnt; ra.rel = rel; ra.ticket = ticket;
    ra.b1_sw = b1_sw; ra.b1_mem = b1_mem; ra.b1_sv = b1_sv;
    ra.b_sw = b_sw;   ra.b_mem = b_mem;   ra.b_sv = b_sv;
    ra.w1_sw = w1_sw; ra.w1_mem = w1_mem; ra.w1_sv = w1_sv;
    ra.letters = letters;
    recurrence<<<NGRID, 384, 0, stream>>>(ra);

    head_gemm<<<dim3(8, 16), 128, 0, stream>>>(Sfin, SS, 750, wp1, bp1, Y1, 450);
    head_gemm<<<dim3(5, 16), 128, 0, stream>>>(Y1, 450, 450, wp2, bp2, Y2, 300);
    head_gemm<<<dim3(4, 16), 128, 0, stream>>>(Y2, 300, 300, wp3, bp3, Y3, 200);
    head_gemm<<<dim3(2, 16), 128, 0, stream>>>(Y3, 200, 200, wp4, bp4, Y4, 100);
    head_final<<<BSZ, 64, 0, stream>>>(Y4, wp5, bp5, (float*)d_out);
}

// Round 9
// 2085.671 us; speedup vs baseline: 1.5714x; 1.3676x over previous
//
#include <hip/hip_runtime.h>
#include <math.h>

#define BSZ 512
#define NV 30
#define NT 24
#define SS 768                  // state row stride (x: 0..249, m: 250..749, pad: 750..767)
#define PL (80 * 24 * 512)      // packed ushorts per (layer, half): 80 nb-blocks x 24 kc x 512
#define NBLK 256
#define NSTEP 144

typedef __attribute__((ext_vector_type(8))) short bf16x8;
typedef __attribute__((ext_vector_type(4))) float f32x4;
typedef __attribute__((ext_vector_type(4))) unsigned u32x4;

__device__ __forceinline__ unsigned short f2bf(float f) {
    unsigned u = __float_as_uint(f);
    u += 0x7fffu + ((u >> 16) & 1u);        // round-to-nearest-even
    return (unsigned short)(u >> 16);
}
__device__ __forceinline__ float bf2f(unsigned short h) {
    return __uint_as_float(((unsigned)h) << 16);
}
__device__ __forceinline__ f32x4 mm(bf16x8 a, bf16x8 b, f32x4 c) {
    return __builtin_amdgcn_mfma_f32_16x16x32_bf16(a, b, c, 0, 0, 0);
}
#define LD8(p) (*(const bf16x8*)(const void*)(p))

// coalesced 16B load, L1-bypass (sc0) so intra-XCD L2 state is never served stale from L1.
// NOTE: result arrives only after an explicit s_waitcnt vmcnt(0) + sched_barrier fence.
__device__ __forceinline__ u32x4 ld16_sc0(const void* p) {
    u32x4 r;
    asm volatile("global_load_dwordx4 %0, %1, off sc0" : "=v"(r) : "v"(p) : "memory");
    return r;
}

struct RecArgs {
    const unsigned short* Pw;
    unsigned* A0; unsigned* A1;      // interleaved state planes: elem = hi | (lo<<16)
    float* Sfin;
    unsigned int* cnt;               // per-XCD barrier counters, stride 32 u32
    unsigned int* rel;               // per-XCD release words, stride 32 u32
    unsigned int* ticket;            // per-XCD tickets [8]
    const float* b1_sw; const float* b1_mem; const float* b1_sv;
    const float* b_sw;  const float* b_mem;  const float* b_sv;
    const float* w1_sw; const float* w1_mem; const float* w1_sv;
    const int* letters;
};

// ---------------- zero ----------------
__global__ void zero_kernel(float* p, int n) {
    int i = blockIdx.x * blockDim.x + threadIdx.x;
    int st = gridDim.x * blockDim.x;
    for (; i < n; i += st) p[i] = 0.f;
}

// ---------------- one-time weight pack: fp32 [750][N] -> hi/lo bf16 MFMA-B layout ----------------
// Phi[((nb*24 + kc)*64 + lane)*8 + j] = bf16_hi(W[kc*32 + (lane>>4)*8 + j][nb*16 + (lane&15)])
// nb 0..31 = sw (N=500 pad 512), 32..63 = mem, 64..79 = sv (N=250 pad 256). k>=750 zero-padded.
__launch_bounds__(64)
__global__ void pack_weights(const float* __restrict__ Wsw, const float* __restrict__ Wmem,
                             const float* __restrict__ Wsv,
                             unsigned short* __restrict__ Phi, unsigned short* __restrict__ Plo)
{
    const int kc = blockIdx.x;   // 0..23
    const int nb = blockIdx.y;   // 0..79
    const int l  = threadIdx.x;  // 0..63
    const int g = l >> 4, c = l & 15;
    const float* W; int N, nbl;
    if (nb < 32)      { W = Wsw;  N = 500; nbl = nb; }
    else if (nb < 64) { W = Wmem; N = 500; nbl = nb - 32; }
    else              { W = Wsv;  N = 250; nbl = nb - 64; }
    const int n = nbl * 16 + c;
    unsigned short h8[8], l8[8];
    #pragma unroll
    for (int j = 0; j < 8; ++j) {
        const int k = kc * 32 + g * 8 + j;
        const float w = (k < 750 && n < N) ? W[(size_t)k * N + n] : 0.f;
        const unsigned short h = f2bf(w);
        h8[j] = h;
        l8[j] = f2bf(w - bf2f(h));
    }
    const size_t off = ((size_t)nb * 24 + kc) * 512 + (size_t)l * 8;
    #pragma unroll
    for (int j = 0; j < 8; ++j) { Phi[off + j] = h8[j]; Plo[off + j] = l8[j]; }
}

// ---------------- persistent recurrence: all 24*6 layers in one kernel ----------------
// ROW-PER-XCD partition (r8 post-mortem: the flat 19-24us/step across r3-r8 was the
// agent-scope state exchange executing at the MALL -- FETCH was invariant to weight
// partitioning). Here XCD x owns rows x*64..+63 for ALL steps: state never crosses an
// XCD. Grid 256 x 384 thr; LDS padded to 80KB forces 1 block/CU => exact pigeonhole
// 32 blocks/XCD (ticket via HW XCC_ID, r8-proven). Block j: quarter=j>>3 (16 rows,
// m0 = xcd*64+quarter*16, A staged to 48KB swizzled LDS via coalesced sc0 dwordx4),
// p=j&7; wave w -> column task t=p*6+w of 48 (t<32: sw+mem pair u=t, gating epilogue
// wave-local, m in regs; else sv u=t-32). State I/O: plain stores (write-through L1 ->
// XCD L2) + sc0 loads (L1 bypass, L2 hit ~200cy). Weights: full 3.93MB/layer streamed
// per XCD from LLC (ordinary cached reads, unroll-4 hides latency). Barrier: per-XCD,
// 32 RMW arrivals + read-only release (MALL, but only 1 word/block/step).
// Per-output MFMA order identical to r3..r8 => absmax canary 2.441e-4 must hold.
__launch_bounds__(384)
__global__ void recurrence(RecArgs A)
{
    __shared__ __align__(16) unsigned char lds[81920];   // 48KB used; 80KB forces 1 block/CU
    __shared__ int s_j;
    const int tid = threadIdx.x;

    int xcd;
    asm volatile("s_getreg_b32 %0, hwreg(HW_REG_XCC_ID)" : "=s"(xcd));
    xcd &= 7;
    if (tid == 0) s_j = (int)atomicAdd(A.ticket + xcd, 1u);
    __syncthreads();
    const int j = s_j;                   // 0..31 within this XCD (exact pigeonhole)
    const int quarter = j >> 3, p = j & 7;
    const int m0 = xcd * 64 + quarter * 16;

    const int w  = tid >> 6;             // wave 0..5
    const int l6 = tid & 63;
    const int g = l6 >> 4, c = l6 & 15;
    const int asw = (c & 7) << 4;        // FRAG XOR bits (row&7 == c&7)

    const int tk = p * 6 + w;            // column task 0..47
    const bool ispair = (tk < 32);
    const int su = ispair ? tk : (tk - 32);
    const int col = su * 16 + c;         // pair: m-col (valid<500); sv: x-col (valid<250)

    const size_t lnoff = (size_t)l6 * 8;
    const size_t bofs0 = ((size_t)((ispair ? tk : 64 + su) * 24)) * 512 + lnoff;
    const size_t bofs1 = ((size_t)((32 + tk) * 24)) * 512 + lnoff;   // pair only

    unsigned* cntw = A.cnt + (xcd << 5);
    unsigned* relw = A.rel + (xcd << 5);

    float mreg[4];
    #pragma unroll
    for (int i = 0; i < 4; ++i) mreg[i] = 0.f;

#define FRAG(pl, kc) (*(const bf16x8*)(lds + (pl) * 24576 + c * 1536 + ((((kc) * 64) + g * 16) ^ asw)))

    #pragma unroll 1
    for (int step = 0; step < NSTEP; ++step) {
        const int tt = step / 6;
        const int l = step - 6 * tt;
        const unsigned* Ain = (step & 1) ? A.A1 : A.A0;
        unsigned* Aout      = (step & 1) ? A.A0 : A.A1;
        const unsigned short* Phi = A.Pw + (size_t)l * 2 * PL;
        const unsigned short* Plo = Phi + PL;
        const bool more = (step != NSTEP - 1);

        // ---- stage A rows [m0, m0+16): 16 rows x 3072B = 3072 16B-chunks / 384 thr = 8
        // coalesced sc0 dwordx4 loads per thread; explicit vmcnt fence (inline-asm loads
        // are NOT dependency-tracked by the compiler); unpack hi/lo into swizzled planes.
        {
            const unsigned char* src = (const unsigned char*)(Ain + (size_t)m0 * SS);
            u32x4 tmp[8];
            #pragma unroll
            for (int jj = 0; jj < 8; ++jj) {
                const int f = tid + jj * 384;
                const int row = f / 192;
                const int q = f - row * 192;
                tmp[jj] = ld16_sc0(src + row * 3072 + q * 16);
            }
            asm volatile("s_waitcnt vmcnt(0)" ::: "memory");
            __builtin_amdgcn_sched_barrier(0);
            #pragma unroll
            for (int jj = 0; jj < 8; ++jj) {
                const int f = tid + jj * 384;
                const int row = f / 192;
                const int q = f - row * 192;
                const int d = row * 1536 + ((q * 8) ^ ((row & 7) << 4));
                const u32x4 v = tmp[jj];
                const unsigned h0 = (v[0] & 0xffffu) | (v[1] << 16);
                const unsigned h1 = (v[2] & 0xffffu) | (v[3] << 16);
                const unsigned o0 = (v[0] >> 16) | (v[1] & 0xffff0000u);
                const unsigned o1 = (v[2] >> 16) | (v[3] & 0xffff0000u);
                *(unsigned long long*)(lds + d)         = (unsigned long long)h0 | ((unsigned long long)h1 << 32);
                *(unsigned long long*)(lds + 24576 + d) = (unsigned long long)o0 | ((unsigned long long)o1 << 32);
            }
        }
        __syncthreads();

        if (ispair) {
            f32x4 z0 = (f32x4)0.f, z1 = (f32x4)0.f;
            #pragma unroll 4
            for (int kc = 0; kc < 24; ++kc) {
                const bf16x8 ah = FRAG(0, kc);
                const bf16x8 al = FRAG(1, kc);
                const size_t k5 = (size_t)kc * 512;
                const bf16x8 bh0 = LD8(Phi + bofs0 + k5);
                const bf16x8 bl0 = LD8(Plo + bofs0 + k5);
                const bf16x8 bh1 = LD8(Phi + bofs1 + k5);
                const bf16x8 bl1 = LD8(Plo + bofs1 + k5);
                z0 = mm(ah, bh0, z0); z0 = mm(al, bh0, z0); z0 = mm(ah, bl0, z0);
                z1 = mm(ah, bh1, z1); z1 = mm(al, bh1, z1); z1 = mm(ah, bl1, z1);
            }
            if (col < 500) {
                const float* bswp  = l ? A.b_sw  + (size_t)(l - 1) * 500 : A.b1_sw;
                const float* bmemp = l ? A.b_mem + (size_t)(l - 1) * 500 : A.b1_mem;
                const float bs = bswp[col];
                const float bm = bmemp[col];
                #pragma unroll
                for (int r = 0; r < 4; ++r) {
                    const int row = m0 + g * 4 + r;
                    float zs = z0[r] + bs;
                    float zm = z1[r] + bm;
                    if (l == 0) {
                        const int lt = A.letters[row * NT + tt];
                        zs += A.w1_sw[(size_t)(750 + lt) * 500 + col];
                        zm += A.w1_mem[(size_t)(750 + lt) * 500 + col];
                    }
                    const float s = 1.f / (1.f + expf(-zs));
                    const float mn = mreg[r] * s + tanhf(zm) * (1.f - s);
                    mreg[r] = mn;
                    const size_t o = (size_t)row * SS + 250 + col;
                    const unsigned short h = f2bf(mn);
                    const unsigned short lo2 = f2bf(mn - bf2f(h));
                    Aout[o] = (unsigned)h | ((unsigned)lo2 << 16);   // plain store -> XCD L2
                    if (step == NSTEP - 1) A.Sfin[o] = mn;
                }
            }
        } else {
            f32x4 z0 = (f32x4)0.f;
            #pragma unroll 4
            for (int kc = 0; kc < 24; ++kc) {
                const bf16x8 ah = FRAG(0, kc);
                const bf16x8 al = FRAG(1, kc);
                const size_t k5 = (size_t)kc * 512;
                const bf16x8 bh = LD8(Phi + bofs0 + k5);
                const bf16x8 bl = LD8(Plo + bofs0 + k5);
                z0 = mm(ah, bh, z0); z0 = mm(al, bh, z0); z0 = mm(ah, bl, z0);
            }
            if (col < 250) {
                const float* bsvp = l ? A.b_sv + (size_t)(l - 1) * 250 : A.b1_sv;
                const float bv = bsvp[col];
                #pragma unroll
                for (int r = 0; r < 4; ++r) {
                    const int row = m0 + g * 4 + r;
                    float z = z0[r] + bv;
                    if (l == 0) {
                        const int lt = A.letters[row * NT + tt];
                        z += A.w1_sv[(size_t)(750 + lt) * 250 + col];
                    }
                    const float x = tanhf(z);
                    const size_t o = (size_t)row * SS + col;
                    const unsigned short h = f2bf(x);
                    const unsigned short lo2 = f2bf(x - bf2f(h));
                    Aout[o] = (unsigned)h | ((unsigned)lo2 << 16);   // plain store -> XCD L2
                    if (step == NSTEP - 1) A.Sfin[o] = x;
                }
            }
        }

        // ---- per-XCD barrier: stores drained to L2 by the pre-barrier vmcnt(0); then
        // 32 RMW arrivals on this XCD's counter + read-only release word.
        __syncthreads();
        if (more) {
            if (tid == 0) {
                const unsigned v = __hip_atomic_fetch_add(cntw, 1u, __ATOMIC_RELAXED, __HIP_MEMORY_SCOPE_AGENT);
                if (v == 32u * (unsigned)(step + 1) - 1u) {
                    __hip_atomic_store(relw, (unsigned)(step + 1), __ATOMIC_RELAXED, __HIP_MEMORY_SCOPE_AGENT);
                } else {
                    while (__hip_atomic_load(relw, __ATOMIC_RELAXED, __HIP_MEMORY_SCOPE_AGENT) < (unsigned)(step + 1))
                        __builtin_amdgcn_s_sleep(2);
                }
            }
            __syncthreads();
        }
    }
#undef FRAG
}

// ---------------- head GEMM: Y = tanh(X @ W + b) (fp32) ----------------
__launch_bounds__(128)
__global__ void head_gemm(const float* __restrict__ X, int ldx, int K,
                          const float* __restrict__ W, const float* __restrict__ bias,
                          float* __restrict__ Y, int N)
{
    const int tid = threadIdx.x;
    const int m0 = blockIdx.y * 32;
    const int n0 = blockIdx.x * 64;

    __shared__ float As[2][32][36];
    __shared__ float Bs[2][32][68];

    const int tx = tid & 15, ty = tid >> 4;
    const int kl = tid & 31, rl = tid >> 5;
    const int cl = tid & 63, kg = tid >> 6;
    const bool cok = (n0 + cl) < N;

    float acc[4][4] = {{0.f}};
    float ar[8], br[16];

    {
        const float* a = X + (size_t)(m0 + rl) * ldx + kl;
        #pragma unroll
        for (int i = 0; i < 8; i++) ar[i] = a[(size_t)(4 * i) * ldx];
        #pragma unroll
        for (int i = 0; i < 16; i++)
            br[i] = cok ? W[(size_t)(kg + 2 * i) * N + n0 + cl] : 0.f;
        #pragma unroll
        for (int i = 0; i < 8; i++) As[0][kl][rl + 4 * i] = ar[i];
        #pragma unroll
        for (int i = 0; i < 16; i++) Bs[0][kg + 2 * i][cl] = br[i];
    }
    __syncthreads();

    int buf = 0;
    const int NK = (K + 31) / 32;
    #pragma unroll 1
    for (int kt = 0; kt < NK; kt++) {
        const bool more = (kt + 1 < NK);
        if (more) {
            const int k0 = (kt + 1) * 32;
            const bool ka = (k0 + kl) < K;
            const float* a = X + (size_t)(m0 + rl) * ldx + k0 + kl;
            #pragma unroll
            for (int i = 0; i < 8; i++) ar[i] = ka ? a[(size_t)(4 * i) * ldx] : 0.f;
            #pragma unroll
            for (int i = 0; i < 16; i++) {
                const int kk = k0 + kg + 2 * i;
                br[i] = (cok && kk < K) ? W[(size_t)kk * N + n0 + cl] : 0.f;
            }
        }
        #pragma unroll
        for (int kk = 0; kk < 32; kk++) {
            float4 av = *(const float4*)&As[buf][kk][ty * 4];
            float4 bv = *(const float4*)&Bs[buf][kk][tx * 4];
            const float aa[4] = {av.x, av.y, av.z, av.w};
            const float bb[4] = {bv.x, bv.y, bv.z, bv.w};
            #pragma unroll
            for (int i = 0; i < 4; i++)
                #pragma unroll
                for (int j = 0; j < 4; j++)
                    acc[i][j] = fmaf(aa[i], bb[j], acc[i][j]);
        }
        if (more) {
            #pragma unroll
            for (int i = 0; i < 8; i++) As[buf ^ 1][kl][rl + 4 * i] = ar[i];
            #pragma unroll
            for (int i = 0; i < 16; i++) Bs[buf ^ 1][kg + 2 * i][cl] = br[i];
            __syncthreads();
            buf ^= 1;
        }
    }

    #pragma unroll
    for (int i = 0; i < 4; i++) {
        const int b = m0 + ty * 4 + i;
        #pragma unroll
        for (int j = 0; j < 4; j++) {
            const int n = n0 + tx * 4 + j;
            if (n < N) Y[(size_t)b * N + n] = tanhf(acc[i][j] + bias[n]);
        }
    }
}

// ---------------- final: logits (K=100, N=30) + softmax ----------------
__global__ void head_final(const float* __restrict__ Y4, const float* __restrict__ W,
                           const float* __restrict__ bias, float* __restrict__ out)
{
    const int row = blockIdx.x;
    __shared__ float y[100];
    __shared__ float z[NV];
    for (int k = threadIdx.x; k < 100; k += 64) y[k] = Y4[row * 100 + k];
    __syncthreads();
    const int n = threadIdx.x;
    if (n < NV) {
        float acc = bias[n];
        for (int k = 0; k < 100; k++) acc = fmaf(y[k], W[k * NV + n], acc);
        z[n] = acc;
    }
    __syncthreads();
    if (n < NV) {
        float mx = -1e30f;
        for (int i = 0; i < NV; i++) mx = fmaxf(mx, z[i]);
        float sum = 0.f;
        for (int i = 0; i < NV; i++) sum += expf(z[i] - mx);
        out[row * NV + n] = expf(z[n] - mx) / sum;
    }
}

extern "C" void kernel_launch(void* const* d_in, const int* in_sizes, int n_in,
                              void* d_out, int out_size, void* d_ws, size_t ws_size,
                              hipStream_t stream)
{
    const int*   letters = (const int*)  d_in[0];
    const float* w1_sv   = (const float*)d_in[1];
    const float* b1_sv   = (const float*)d_in[2];
    const float* w1_mem  = (const float*)d_in[3];
    const float* b1_mem  = (const float*)d_in[4];
    const float* w1_sw   = (const float*)d_in[5];
    const float* b1_sw   = (const float*)d_in[6];
    const float* w_sv    = (const float*)d_in[7];
    const float* b_sv    = (const float*)d_in[8];
    const float* w_mem   = (const float*)d_in[9];
    const float* b_mem   = (const float*)d_in[10];
    const float* w_sw    = (const float*)d_in[11];
    const float* b_sw    = (const float*)d_in[12];
    const float* wp1 = (const float*)d_in[13]; const float* bp1 = (const float*)d_in[14];
    const float* wp2 = (const float*)d_in[15]; const float* bp2 = (const float*)d_in[16];
    const float* wp3 = (const float*)d_in[17]; const float* bp3 = (const float*)d_in[18];
    const float* wp4 = (const float*)d_in[19]; const float* bp4 = (const float*)d_in[20];
    const float* wp5 = (const float*)d_in[21]; const float* bp5 = (const float*)d_in[22];

    // workspace layout
    float* Sfin = (float*)d_ws;                                   // BSZ*SS f32 (written at final step)
    float* cntf = Sfin + (size_t)BSZ * SS;                        // 1024 u32: cnt[8x32], rel[8x32], ticket[8]
    unsigned int* cnt = (unsigned int*)cntf;
    unsigned int* rel = cnt + 256;
    unsigned int* ticket = cnt + 512;
    unsigned* A0 = (unsigned*)(cntf + 1024);                      // interleaved state plane 0
    unsigned* A1 = A0 + (size_t)BSZ * SS;                         // interleaved state plane 1
    unsigned short* Pw = (unsigned short*)(A1 + (size_t)BSZ * SS);// 12 * PL ushorts
    float* Y1 = (float*)(Pw + (size_t)12 * PL);
    float* Y2 = Y1 + (size_t)BSZ * 450;
    float* Y3 = Y2 + (size_t)BSZ * 300;
    float* Y4 = Y3 + (size_t)BSZ * 200;

    // zero barrier words + tickets + both interleaved state planes (pad cols stay 0 forever)
    zero_kernel<<<512, 256, 0, stream>>>(cntf, 1024 + 2 * BSZ * SS);

    // one-time weight packing
    pack_weights<<<dim3(24, 80), 64, 0, stream>>>(w1_sw, w1_mem, w1_sv, Pw, Pw + PL);
    for (int l = 1; l < 6; ++l)
        pack_weights<<<dim3(24, 80), 64, 0, stream>>>(
            w_sw  + (size_t)(l - 1) * 750 * 500,
            w_mem + (size_t)(l - 1) * 750 * 500,
            w_sv  + (size_t)(l - 1) * 750 * 250,
            Pw + (size_t)l * 2 * PL, Pw + (size_t)l * 2 * PL + PL);

    RecArgs ra;
    ra.Pw = Pw;
    ra.A0 = A0; ra.A1 = A1;
    ra.Sfin = Sfin; ra.cnt = cnt; ra.rel = rel; ra.ticket = ticket;
    ra.b1_sw = b1_sw; ra.b1_mem = b1_mem; ra.b1_sv = b1_sv;
    ra.b_sw = b_sw;   ra.b_mem = b_mem;   ra.b_sv = b_sv;
    ra.w1_sw = w1_sw; ra.w1_mem = w1_mem; ra.w1_sv = w1_sv;
    ra.letters = letters;
    recurrence<<<NBLK, 384, 0, stream>>>(ra);

    head_gemm<<<dim3(8, 16), 128, 0, stream>>>(Sfin, SS, 750, wp1, bp1, Y1, 450);
    head_gemm<<<dim3(5, 16), 128, 0, stream>>>(Y1, 450, 450, wp2, bp2, Y2, 300);
    head_gemm<<<dim3(4, 16), 128, 0, stream>>>(Y2, 300, 300, wp3, bp3, Y3, 200);
    head_gemm<<<dim3(2, 16), 128, 0, stream>>>(Y3, 200, 200, wp4, bp4, Y4, 100);
    head_final<<<BSZ, 64, 0, stream>>>(Y4, wp5, bp5, (float*)d_out);
}